// Round 3
// baseline (603.020 us; speedup 1.0000x reference)
//
#include <hip/hip_runtime.h>

typedef __attribute__((ext_vector_type(8))) short short8;
typedef __attribute__((ext_vector_type(4))) float v4f;

#define C_CH 128
#define S_SP 16384
#define NSLICE 16
#define KTOT 384

__device__ inline float bf2f(unsigned short u) {
  union { unsigned int i; float f; } v; v.i = ((unsigned int)u) << 16; return v.f;
}
__device__ inline unsigned short f2bf(float f) {
  union { float f; unsigned int i; } v; v.f = f;
  unsigned int u = v.i;
  return (unsigned short)((u + 0x7FFFu + ((u >> 16) & 1u)) >> 16);
}

__device__ inline void gload_lds16(const unsigned short* g, unsigned short* l) {
  __builtin_amdgcn_global_load_lds(
      (const __attribute__((address_space(1))) void*)g,
      (__attribute__((address_space(3))) void*)l, 16, 0, 0);
}

// ---- weight repack: Wr[o][t*128+c] = bf16(w[o][c][t]); bias fp32 copy --------
__global__ __launch_bounds__(256) void repack_kernel(
    const float* __restrict__ wq, const float* __restrict__ wk,
    const float* __restrict__ wv, const float* __restrict__ wp,
    const float* __restrict__ bq, const float* __restrict__ bk,
    const float* __restrict__ bv, const float* __restrict__ bp,
    unsigned short* __restrict__ Wr, float* __restrict__ biasf)
{
  int i = blockIdx.x * 256 + threadIdx.x;
  const int WN = 4 * 49152;
  if (i < WN) {
    int m = i / 49152;
    int r = i % 49152;
    int o = r / 384, k = r % 384;
    int t = k >> 7, c = k & 127;
    const float* w = (m == 0) ? wq : (m == 1) ? wk : (m == 2) ? wv : wp;
    Wr[i] = f2bf(w[o * 384 + c * 3 + t]);
  } else if (i < WN + 512) {
    int j = i - WN;
    int m = j >> 7, o = j & 127;
    const float* bb = (m == 0) ? bq : (m == 1) ? bk : (m == 2) ? bv : bp;
    biasf[j] = bb[o];
  }
}

// ---- ingress: fp32 [R][C] -> bf16 [C][R], per z-slice (R=128, C=16384) -------
__global__ __launch_bounds__(256) void transpose_f2b_kernel(
    const float* __restrict__ in, unsigned short* __restrict__ out,
    int R, int C)
{
  __shared__ unsigned short t[64][72];
  int tid = threadIdx.x;
  size_t slice = blockIdx.z;
  const float* ip = in + slice * (size_t)R * C;
  unsigned short* op = out + slice * (size_t)R * C;
  int c0 = blockIdx.x * 64, r0 = blockIdx.y * 64;
#pragma unroll
  for (int p = 0; p < 4; ++p) {
    int id = tid + p * 256;
    int row = id >> 4, col = (id & 15) * 4;
    float4 v = *(const float4*)(ip + (size_t)(r0 + row) * C + c0 + col);
    t[row][col + 0] = f2bf(v.x);
    t[row][col + 1] = f2bf(v.y);
    t[row][col + 2] = f2bf(v.z);
    t[row][col + 3] = f2bf(v.w);
  }
  __syncthreads();
#pragma unroll
  for (int p = 0; p < 2; ++p) {
    int id = tid + p * 256;
    int crow = id >> 3, rcol = (id & 7) * 8;
    uint4 v;
    v.x = (unsigned)t[rcol + 0][crow] | ((unsigned)t[rcol + 1][crow] << 16);
    v.y = (unsigned)t[rcol + 2][crow] | ((unsigned)t[rcol + 3][crow] << 16);
    v.z = (unsigned)t[rcol + 4][crow] | ((unsigned)t[rcol + 5][crow] << 16);
    v.w = (unsigned)t[rcol + 6][crow] | ((unsigned)t[rcol + 7][crow] << 16);
    *(uint4*)(op + (size_t)(c0 + crow) * R + r0 + rcol) = v;
  }
}

// ---- QKV conv, z-fused: stage x-tile ONCE, MFMA against 3 weight sets --------
// Block: slice x s-tile(64). Wave w: o-strip [w*32,w*32+32) for all z.
// Phases ap = t*2+sub (K=64), valid contiguous [lo,hi].
// B(x) staged 2-ahead (tri-buffer, 2 gload_lds/thread/phase);
// A(weights) prefetched 1-ahead into 2 rotating reg sets (12 short8 each).
// Steady-state wait vmcnt(2) (= in-flight next-stage), vmcnt(0) at hi.
__global__ __launch_bounds__(256, 2) void conv_qkv_kernel(
    const unsigned short* __restrict__ inT,
    const unsigned short* __restrict__ Wr_all,
    const float* __restrict__ bias_all,
    unsigned short* __restrict__ outQ)
{
  __shared__ unsigned short Blds[3][64 * 64];  // 3 x 8 KB, linear (swizzled)

  int tid = threadIdx.x;
  int s0 = blockIdx.x * 64;
  int slice = blockIdx.y;
  int b = slice >> 3, l = slice & 7;
  int lh = l & 3;
  int t_lo = (lh == 0) ? 1 : 0;
  int t_hi = (lh == 3) ? 1 : 2;
  int lo = t_lo * 2, hi = t_hi * 2 + 1;

  int w = tid >> 6, lane = tid & 63;
  int quad = lane >> 4, l15 = lane & 15;
  int srow_i = lane >> 3;
  int scs = (lane & 7) ^ srow_i;

  v4f acc[3][2][4];
#pragma unroll
  for (int z_ = 0; z_ < 3; ++z_)
#pragma unroll
    for (int i = 0; i < 2; ++i)
#pragma unroll
      for (int j = 0; j < 4; ++j)
        acc[z_][i][j] = (v4f){0.f, 0.f, 0.f, 0.f};

  short8 afA[12], afB[12];

#define STAGE(ap, bsel) do {                                                   \
    int t_ = (ap) >> 1;                                                        \
    const unsigned short* gb_ =                                                \
        inT + ((size_t)(b * 8 + l - 1 + t_) * S_SP + s0) * C_CH +              \
        ((ap) & 1) * 64;                                                       \
    _Pragma("unroll")                                                          \
    for (int q_ = 0; q_ < 2; ++q_)                                             \
      gload_lds16(gb_ + (size_t)((w * 2 + q_) * 8 + srow_i) * C_CH + scs * 8,  \
                  &Blds[bsel][(w * 2 + q_) * 512]);                            \
  } while (0)

#define AFLOAD(ap, set) do {                                                   \
    _Pragma("unroll")                                                          \
    for (int z_ = 0; z_ < 3; ++z_)                                             \
      _Pragma("unroll")                                                        \
      for (int i_ = 0; i_ < 2; ++i_)                                           \
        _Pragma("unroll")                                                      \
        for (int ks_ = 0; ks_ < 2; ++ks_)                                      \
          set[z_ * 4 + i_ * 2 + ks_] = *(const short8*)(                       \
              Wr_all + (size_t)z_ * 49152 +                                    \
              (size_t)(w * 32 + i_ * 16 + l15) * KTOT +                        \
              (ap) * 64 + ks_ * 32 + quad * 8);                                \
  } while (0)

  // prologue: ST(lo), AF(lo)->afA, ST(lo+1)   (order pinned for vmcnt math)
  {
    int ap0 = lo;
    STAGE(ap0, ap0 % 3);
    __builtin_amdgcn_sched_barrier(0);
    AFLOAD(ap0, afA);
    __builtin_amdgcn_sched_barrier(0);
    STAGE(ap0 + 1, (ap0 + 1) % 3);
    __builtin_amdgcn_sched_barrier(0);
  }

#define PHASE(ap, CUR, NXT)                                                    \
  if ((ap) >= lo && (ap) <= hi) {                                              \
    if ((ap) == hi) { asm volatile("s_waitcnt vmcnt(0)" ::: "memory"); }       \
    else            { asm volatile("s_waitcnt vmcnt(2)" ::: "memory"); }       \
    __builtin_amdgcn_s_barrier();                                              \
    if ((ap) + 1 <= hi) { AFLOAD((ap) + 1, NXT);                               \
                          __builtin_amdgcn_sched_barrier(0); }                 \
    if ((ap) + 2 <= hi) { STAGE((ap) + 2, ((ap) + 2) % 3);                     \
                          __builtin_amdgcn_sched_barrier(0); }                 \
    const unsigned short* Bp_ = &Blds[(ap) % 3][0];                            \
    _Pragma("unroll")                                                          \
    for (int ks = 0; ks < 2; ++ks) {                                           \
      short8 bfr[4];                                                           \
      _Pragma("unroll")                                                        \
      for (int j4 = 0; j4 < 4; ++j4)                                           \
        bfr[j4] = *(const short8*)(                                            \
            Bp_ + (j4 * 16 + l15) * 64 +                                       \
            (((ks * 4 + quad) ^ (l15 & 7)) * 8));                              \
      _Pragma("unroll")                                                        \
      for (int z_ = 0; z_ < 3; ++z_)                                           \
        _Pragma("unroll")                                                      \
        for (int i = 0; i < 2; ++i)                                            \
          _Pragma("unroll")                                                    \
          for (int j4 = 0; j4 < 4; ++j4)                                       \
            acc[z_][i][j4] = __builtin_amdgcn_mfma_f32_16x16x32_bf16(          \
                CUR[z_ * 4 + i * 2 + ks], bfr[j4], acc[z_][i][j4], 0, 0, 0);   \
    }                                                                          \
  }

  PHASE(0, afA, afB)
  PHASE(1, afB, afA)
  PHASE(2, afA, afB)
  PHASE(3, afB, afA)
  PHASE(4, afA, afB)
  PHASE(5, afB, afA)

#undef PHASE
#undef AFLOAD
#undef STAGE

  // ---- epilogue: bias + bf16 pack + store to Q/K/V --------------------------
#pragma unroll
  for (int z_ = 0; z_ < 3; ++z_) {
    unsigned short* outT = outQ + (size_t)z_ * ((size_t)NSLICE * S_SP * C_CH);
    const float* bias = bias_all + z_ * 128;
#pragma unroll
    for (int i = 0; i < 2; ++i) {
      int obase = w * 32 + i * 16 + quad * 4;
      float4 bb = *(const float4*)(bias + obase);
#pragma unroll
      for (int j = 0; j < 4; ++j) {
        int s = s0 + j * 16 + l15;
        float f0 = acc[z_][i][j].x + bb.x;
        float f1 = acc[z_][i][j].y + bb.y;
        float f2 = acc[z_][i][j].z + bb.z;
        float f3 = acc[z_][i][j].w + bb.w;
        uint2 st;
        st.x = (unsigned)f2bf(f0) | ((unsigned)f2bf(f1) << 16);
        st.y = (unsigned)f2bf(f2) | ((unsigned)f2bf(f3) << 16);
        *(uint2*)(outT + ((size_t)slice * S_SP + s) * C_CH + obase) = st;
      }
    }
  }
}

// ---- projection conv, swapped operands: A = Y (s rows), B = weights (o cols) -
// C/D: row = s (quad*4+reg, 4 consecutive!), col = o (l15) -> direct coalesced
// fp32 [o][s] float4 stores into d_out. Deletes the egress transpose kernel.
// Y tile [128 s][64 k] staged 2-ahead (tri-buffer, 4 gload_lds/thread/phase);
// weight B-frags prefetched 1-ahead into 2 rotating sets (16 short8 each).
// Steady wait vmcnt(4), vmcnt(0) at hi.
__global__ __launch_bounds__(256, 2) void conv_proj_kernel(
    const unsigned short* __restrict__ YT,
    const unsigned short* __restrict__ Wp,
    const float* __restrict__ biasp,
    float* __restrict__ dout)
{
  __shared__ unsigned short Alds[3][128 * 64];  // 3 x 16 KB

  int tid = threadIdx.x;
  int s0 = blockIdx.x * 128;
  int slice = blockIdx.y;
  int b = slice >> 3, l = slice & 7;
  int lh = l & 3;
  int t_lo = (lh == 0) ? 1 : 0;
  int t_hi = (lh == 3) ? 1 : 2;
  int lo = t_lo * 2, hi = t_hi * 2 + 1;

  int w = tid >> 6, lane = tid & 63;
  int quad = lane >> 4, l15 = lane & 15;
  int srow_i = lane >> 3;
  int scs = (lane & 7) ^ srow_i;

  v4f acc[2][8];
#pragma unroll
  for (int i = 0; i < 2; ++i)
#pragma unroll
    for (int j = 0; j < 8; ++j)
      acc[i][j] = (v4f){0.f, 0.f, 0.f, 0.f};

  short8 wfA[16], wfB[16];

#define PSTAGE(ap, bsel) do {                                                  \
    int t_ = (ap) >> 1;                                                        \
    const unsigned short* gb_ =                                                \
        YT + ((size_t)(b * 8 + l - 1 + t_) * S_SP + s0) * C_CH +               \
        ((ap) & 1) * 64;                                                       \
    _Pragma("unroll")                                                          \
    for (int q_ = 0; q_ < 4; ++q_)                                             \
      gload_lds16(gb_ + (size_t)((w * 4 + q_) * 8 + srow_i) * C_CH + scs * 8,  \
                  &Alds[bsel][(w * 4 + q_) * 512]);                            \
  } while (0)

#define WLOAD(ap, set) do {                                                    \
    _Pragma("unroll")                                                          \
    for (int j_ = 0; j_ < 8; ++j_)                                             \
      _Pragma("unroll")                                                        \
      for (int ks_ = 0; ks_ < 2; ++ks_)                                        \
        set[j_ * 2 + ks_] = *(const short8*)(                                  \
            Wp + (size_t)(j_ * 16 + l15) * KTOT +                              \
            (ap) * 64 + ks_ * 32 + quad * 8);                                  \
  } while (0)

  {
    int ap0 = lo;
    PSTAGE(ap0, ap0 % 3);
    __builtin_amdgcn_sched_barrier(0);
    WLOAD(ap0, wfA);
    __builtin_amdgcn_sched_barrier(0);
    PSTAGE(ap0 + 1, (ap0 + 1) % 3);
    __builtin_amdgcn_sched_barrier(0);
  }

#define PPHASE(ap, CUR, NXT)                                                   \
  if ((ap) >= lo && (ap) <= hi) {                                              \
    if ((ap) == hi) { asm volatile("s_waitcnt vmcnt(0)" ::: "memory"); }       \
    else            { asm volatile("s_waitcnt vmcnt(4)" ::: "memory"); }       \
    __builtin_amdgcn_s_barrier();                                              \
    if ((ap) + 1 <= hi) { WLOAD((ap) + 1, NXT);                                \
                          __builtin_amdgcn_sched_barrier(0); }                 \
    if ((ap) + 2 <= hi) { PSTAGE((ap) + 2, ((ap) + 2) % 3);                    \
                          __builtin_amdgcn_sched_barrier(0); }                 \
    const unsigned short* Ap_ = &Alds[(ap) % 3][0];                            \
    _Pragma("unroll")                                                          \
    for (int ks = 0; ks < 2; ++ks) {                                           \
      short8 afr[2];                                                           \
      _Pragma("unroll")                                                        \
      for (int i = 0; i < 2; ++i)                                              \
        afr[i] = *(const short8*)(                                             \
            Ap_ + (w * 32 + i * 16 + l15) * 64 +                               \
            (((ks * 4 + quad) ^ (l15 & 7)) * 8));                              \
      _Pragma("unroll")                                                        \
      for (int i = 0; i < 2; ++i)                                              \
        _Pragma("unroll")                                                      \
        for (int j = 0; j < 8; ++j)                                            \
          acc[i][j] = __builtin_amdgcn_mfma_f32_16x16x32_bf16(                 \
              afr[i], CUR[j * 2 + ks], acc[i][j], 0, 0, 0);                    \
    }                                                                          \
  }

  PPHASE(0, wfA, wfB)
  PPHASE(1, wfB, wfA)
  PPHASE(2, wfA, wfB)
  PPHASE(3, wfB, wfA)
  PPHASE(4, wfA, wfB)
  PPHASE(5, wfB, wfA)

#undef PPHASE
#undef WLOAD
#undef PSTAGE

  // ---- epilogue: bias + direct fp32 [o][s] coalesced float4 stores ----------
  float bias_r[8];
#pragma unroll
  for (int j = 0; j < 8; ++j) bias_r[j] = biasp[j * 16 + l15];
#pragma unroll
  for (int i = 0; i < 2; ++i) {
    int s = s0 + w * 32 + i * 16 + quad * 4;
#pragma unroll
    for (int j = 0; j < 8; ++j) {
      int o = j * 16 + l15;
      float4 v;
      v.x = acc[i][j].x + bias_r[j];
      v.y = acc[i][j].y + bias_r[j];
      v.z = acc[i][j].z + bias_r[j];
      v.w = acc[i][j].w + bias_r[j];
      *(float4*)(dout + ((size_t)slice * 128 + o) * 16384 + s) = v;
    }
  }
}

// ---- fused both-direction window attention -----------------------------------
__device__ inline void load16(const unsigned short* p, float* f) {
  uint4 a = *(const uint4*)p;
  uint4 c = *(const uint4*)(p + 8);
  unsigned v[8] = {a.x, a.y, a.z, a.w, c.x, c.y, c.z, c.w};
#pragma unroll
  for (int i = 0; i < 8; ++i) {
    f[2 * i] = bf2f((unsigned short)(v[i] & 0xffffu));
    f[2 * i + 1] = bf2f((unsigned short)(v[i] >> 16));
  }
}

__global__ __launch_bounds__(256) void attn_kernel(
    const unsigned short* __restrict__ QT,
    const unsigned short* __restrict__ KT,
    const unsigned short* __restrict__ VT,
    unsigned short* __restrict__ YT)
{
  int tid = threadIdx.x;
  int wave = tid >> 6, lane = tid & 63;
  int dir = wave & 1;
  int win = blockIdx.x * 2 + (wave >> 1);
  int by = blockIdx.y;
  int b = by >> 2, l0 = by & 3;
  int head = lane >> 3, qi = lane & 7;
  int d0 = win >> 8, h0 = (win >> 4) & 15, w0 = win & 15;
  int lq = l0 + dir * 4;
  int lk = l0 + 4 - dir * 4;
  int sE[8];
#pragma unroll
  for (int e = 0; e < 8; ++e)
    sE[e] = (2 * d0 + (e >> 2)) * 1024 + (2 * h0 + ((e >> 1) & 1)) * 32 + (2 * w0 + (e & 1));

  size_t qbase = ((size_t)(b * 8 + lq) * S_SP + sE[qi]) * C_CH + head * 16;
  size_t kslice = (size_t)(b * 8 + lk) * S_SP;
  float q[16];
  load16(QT + qbase, q);

  float lg[8];
#pragma unroll
  for (int j = 0; j < 8; ++j) {
    float kk[16];
    load16(KT + (kslice + sE[j]) * C_CH + head * 16, kk);
    float d = 0.f;
#pragma unroll
    for (int x = 0; x < 16; ++x) d += q[x] * kk[x];
    lg[j] = d * 0.25f;  // scale = (C/NH)^-0.5 = 1/4
  }
  float m = lg[0];
#pragma unroll
  for (int j = 1; j < 8; ++j) m = fmaxf(m, lg[j]);
  float p[8], sum = 0.f;
#pragma unroll
  for (int j = 0; j < 8; ++j) { p[j] = __expf(lg[j] - m); sum += p[j]; }
  float inv = 1.0f / sum;

  float y[16];
#pragma unroll
  for (int x = 0; x < 16; ++x) y[x] = 0.f;
#pragma unroll
  for (int j = 0; j < 8; ++j) {
    float vv[16];
    load16(VT + (kslice + sE[j]) * C_CH + head * 16, vv);
    float pj = p[j] * inv;
#pragma unroll
    for (int x = 0; x < 16; ++x) y[x] += pj * vv[x];
  }
  uint4 o0, o1;
  o0.x = (unsigned)f2bf(y[0]) | ((unsigned)f2bf(y[1]) << 16);
  o0.y = (unsigned)f2bf(y[2]) | ((unsigned)f2bf(y[3]) << 16);
  o0.z = (unsigned)f2bf(y[4]) | ((unsigned)f2bf(y[5]) << 16);
  o0.w = (unsigned)f2bf(y[6]) | ((unsigned)f2bf(y[7]) << 16);
  o1.x = (unsigned)f2bf(y[8]) | ((unsigned)f2bf(y[9]) << 16);
  o1.y = (unsigned)f2bf(y[10]) | ((unsigned)f2bf(y[11]) << 16);
  o1.z = (unsigned)f2bf(y[12]) | ((unsigned)f2bf(y[13]) << 16);
  o1.w = (unsigned)f2bf(y[14]) | ((unsigned)f2bf(y[15]) << 16);
  *(uint4*)(YT + qbase) = o0;
  *(uint4*)(YT + qbase + 8) = o1;
}

// -------------------------------------------------------------------------------
extern "C" void kernel_launch(void* const* d_in, const int* in_sizes, int n_in,
                              void* d_out, int out_size, void* d_ws, size_t ws_size,
                              hipStream_t stream) {
  const float* x  = (const float*)d_in[0];
  const float* wq = (const float*)d_in[1];
  const float* bq = (const float*)d_in[2];
  const float* wk = (const float*)d_in[3];
  const float* bk = (const float*)d_in[4];
  const float* wv = (const float*)d_in[5];
  const float* bv = (const float*)d_in[6];
  const float* wp = (const float*)d_in[7];
  const float* bp = (const float*)d_in[8];

  char* ws = (char*)d_ws;
  unsigned short* Wr = (unsigned short*)ws;       // 4*49152 bf16 = 393216 B
  float* biasf = (float*)(ws + 393216);           // 4*128 f32   = 2048 B
  size_t off = 395264;
  const size_t TENB = (size_t)NSLICE * S_SP * C_CH * 2;  // 67108864 B per tensor
  unsigned short* xT = (unsigned short*)(ws + off); off += TENB;
  unsigned short* QT = (unsigned short*)(ws + off); off += TENB;
  unsigned short* KT = (unsigned short*)(ws + off); off += TENB;
  unsigned short* VT = (unsigned short*)(ws + off); off += TENB;
  unsigned short* YT = xT;  // xT dead after QKV convs; reuse for attention out

  // 1) repack weights / biases (fp32 -> bf16 / fp32)
  hipLaunchKernelGGL(repack_kernel, dim3(770), dim3(256), 0, stream,
                     wq, wk, wv, wp, bq, bk, bv, bp, Wr, biasf);
  // 2) x fp32 [c][s] -> xT bf16 [s][c]
  hipLaunchKernelGGL(transpose_f2b_kernel, dim3(256, 2, 16), dim3(256), 0, stream,
                     x, xT, 128, 16384);
  // 3) Q,K,V conv, z-fused (stage x once, 3 weight sets)
  hipLaunchKernelGGL(conv_qkv_kernel, dim3(256, 16), dim3(256), 0, stream,
                     xT, Wr, biasf, QT);
  // 4) fused both-direction window attention -> YT
  hipLaunchKernelGGL(attn_kernel, dim3(1024, 8), dim3(256), 0, stream,
                     QT, KT, VT, YT);
  // 5) projection conv, swapped operands -> direct fp32 [o][s] output
  hipLaunchKernelGGL(conv_proj_kernel, dim3(128, 16), dim3(256), 0, stream,
                     YT, Wr + 3 * 49152, biasf + 384, (float*)d_out);
}

// Round 4
// 457.632 us; speedup vs baseline: 1.3177x; 1.3177x over previous
//
#include <hip/hip_runtime.h>

typedef __attribute__((ext_vector_type(8))) short short8;
typedef __attribute__((ext_vector_type(4))) float v4f;

#define C_CH 128
#define S_SP 16384
#define NSLICE 16
#define KTOT 384

__device__ inline float bf2f(unsigned short u) {
  union { unsigned int i; float f; } v; v.i = ((unsigned int)u) << 16; return v.f;
}
__device__ inline unsigned short f2bf(float f) {
  union { float f; unsigned int i; } v; v.f = f;
  unsigned int u = v.i;
  return (unsigned short)((u + 0x7FFFu + ((u >> 16) & 1u)) >> 16);
}

__device__ inline void gload_lds16(const unsigned short* g, unsigned short* l) {
  __builtin_amdgcn_global_load_lds(
      (const __attribute__((address_space(1))) void*)g,
      (__attribute__((address_space(3))) void*)l, 16, 0, 0);
}

// ---- weight repack: Wr[o][t*128+c] = bf16(w[o][c][t]); bias fp32 copy --------
__global__ __launch_bounds__(256) void repack_kernel(
    const float* __restrict__ wq, const float* __restrict__ wk,
    const float* __restrict__ wv, const float* __restrict__ wp,
    const float* __restrict__ bq, const float* __restrict__ bk,
    const float* __restrict__ bv, const float* __restrict__ bp,
    unsigned short* __restrict__ Wr, float* __restrict__ biasf)
{
  int i = blockIdx.x * 256 + threadIdx.x;
  const int WN = 4 * 49152;
  if (i < WN) {
    int m = i / 49152;
    int r = i % 49152;
    int o = r / 384, k = r % 384;
    int t = k >> 7, c = k & 127;
    const float* w = (m == 0) ? wq : (m == 1) ? wk : (m == 2) ? wv : wp;
    Wr[i] = f2bf(w[o * 384 + c * 3 + t]);
  } else if (i < WN + 512) {
    int j = i - WN;
    int m = j >> 7, o = j & 127;
    const float* bb = (m == 0) ? bq : (m == 1) ? bk : (m == 2) ? bv : bp;
    biasf[j] = bb[o];
  }
}

// ---- ingress: fp32 [R][C] -> bf16 [C][R], per z-slice (R=128, C=16384) -------
__global__ __launch_bounds__(256) void transpose_f2b_kernel(
    const float* __restrict__ in, unsigned short* __restrict__ out,
    int R, int C)
{
  __shared__ unsigned short t[64][72];
  int tid = threadIdx.x;
  size_t slice = blockIdx.z;
  const float* ip = in + slice * (size_t)R * C;
  unsigned short* op = out + slice * (size_t)R * C;
  int c0 = blockIdx.x * 64, r0 = blockIdx.y * 64;
#pragma unroll
  for (int p = 0; p < 4; ++p) {
    int id = tid + p * 256;
    int row = id >> 4, col = (id & 15) * 4;
    float4 v = *(const float4*)(ip + (size_t)(r0 + row) * C + c0 + col);
    t[row][col + 0] = f2bf(v.x);
    t[row][col + 1] = f2bf(v.y);
    t[row][col + 2] = f2bf(v.z);
    t[row][col + 3] = f2bf(v.w);
  }
  __syncthreads();
#pragma unroll
  for (int p = 0; p < 2; ++p) {
    int id = tid + p * 256;
    int crow = id >> 3, rcol = (id & 7) * 8;
    uint4 v;
    v.x = (unsigned)t[rcol + 0][crow] | ((unsigned)t[rcol + 1][crow] << 16);
    v.y = (unsigned)t[rcol + 2][crow] | ((unsigned)t[rcol + 3][crow] << 16);
    v.z = (unsigned)t[rcol + 4][crow] | ((unsigned)t[rcol + 5][crow] << 16);
    v.w = (unsigned)t[rcol + 6][crow] | ((unsigned)t[rcol + 7][crow] << 16);
    *(uint4*)(op + (size_t)(c0 + crow) * R + r0 + rcol) = v;
  }
}

// ---- MFMA conv (R2-proven): per-phase A regs (3 rotating sets), tri-buffer B,
// depth-2 counted-vmcnt pipeline. out[slice][s][o] bf16.
__global__ __launch_bounds__(256, 3) void conv_mfma_kernel(
    const unsigned short* __restrict__ inT,
    const unsigned short* __restrict__ Wr_all,
    const float* __restrict__ bias_all,
    unsigned short* __restrict__ outT_all)
{
  __shared__ unsigned short Blds[3][128 * 64];  // 3 x 16 KB, linear (swizzled)

  int z = blockIdx.z;
  const unsigned short* Wr = Wr_all + (size_t)z * 49152;
  const float* bias = bias_all + z * 128;
  unsigned short* outT = outT_all + (size_t)z * NSLICE * S_SP * C_CH;

  int tid = threadIdx.x;
  int s0 = blockIdx.x * 128;
  int slice = blockIdx.y;
  int b = slice >> 3, l = slice & 7;
  int lh = l & 3;
  int t_lo = (lh == 0) ? 1 : 0;
  int t_hi = (lh == 3) ? 1 : 2;
  int lo = t_lo * 2, hi = t_hi * 2 + 1;

  int w = tid >> 6, lane = tid & 63;
  int quad = lane >> 4, l15 = lane & 15;
  int srow_i = lane >> 3;
  int scs = (lane & 7) ^ srow_i;

  v4f acc[2][8];
#pragma unroll
  for (int i = 0; i < 2; ++i)
#pragma unroll
    for (int j = 0; j < 8; ++j)
      acc[i][j] = (v4f){0.f, 0.f, 0.f, 0.f};

  short8 af0[4], af1[4], af2[4];

#define STAGE(ap, bsel) do {                                                   \
    int t_ = (ap) >> 1;                                                        \
    const unsigned short* gb_ =                                                \
        inT + ((size_t)(b * 8 + l - 1 + t_) * S_SP + s0) * C_CH +              \
        ((ap) & 1) * 64;                                                       \
    _Pragma("unroll")                                                          \
    for (int q_ = 0; q_ < 4; ++q_)                                             \
      gload_lds16(gb_ + (size_t)((w * 4 + q_) * 8 + srow_i) * C_CH + scs * 8,  \
                  &Blds[bsel][(w * 4 + q_) * 512]);                            \
  } while (0)

#define AFLOAD(ap, set) do {                                                   \
    _Pragma("unroll")                                                          \
    for (int i_ = 0; i_ < 2; ++i_)                                             \
      _Pragma("unroll")                                                        \
      for (int ks_ = 0; ks_ < 2; ++ks_)                                        \
        set[i_ * 2 + ks_] = *(const short8*)(                                  \
            Wr + (size_t)(w * 32 + i_ * 16 + l15) * KTOT +                     \
            (ap) * 64 + ks_ * 32 + quad * 8);                                  \
  } while (0)

  if (lo == 0) {
    STAGE(0, 0); AFLOAD(0, af0);
    __builtin_amdgcn_sched_barrier(0);
    STAGE(1, 1); AFLOAD(1, af1);
  } else {
    STAGE(2, 2); AFLOAD(2, af2);
    __builtin_amdgcn_sched_barrier(0);
    STAGE(3, 0); AFLOAD(3, af0);
  }

#define PHASE(ap, CURSET, NXTSET)                                              \
  if ((ap) >= lo && (ap) <= hi) {                                              \
    if ((ap) == hi) { asm volatile("s_waitcnt vmcnt(0)" ::: "memory"); }       \
    else            { asm volatile("s_waitcnt vmcnt(8)" ::: "memory"); }       \
    __builtin_amdgcn_s_barrier();                                              \
    if ((ap) + 2 <= hi) { STAGE((ap) + 2, ((ap) + 2) % 3);                     \
                          AFLOAD((ap) + 2, NXTSET); }                          \
    const unsigned short* Bp_ = &Blds[(ap) % 3][0];                            \
    _Pragma("unroll")                                                          \
    for (int ks = 0; ks < 2; ++ks) {                                           \
      _Pragma("unroll")                                                        \
      for (int jg = 0; jg < 2; ++jg) {                                         \
        short8 bfr[4];                                                         \
        _Pragma("unroll")                                                      \
        for (int j4 = 0; j4 < 4; ++j4)                                         \
          bfr[j4] = *(const short8*)(                                          \
              Bp_ + ((jg * 4 + j4) * 16 + l15) * 64 +                          \
              (((ks * 4 + quad) ^ (l15 & 7)) * 8));                            \
        _Pragma("unroll")                                                      \
        for (int i = 0; i < 2; ++i)                                            \
          _Pragma("unroll")                                                    \
          for (int j4 = 0; j4 < 4; ++j4)                                       \
            acc[i][jg * 4 + j4] = __builtin_amdgcn_mfma_f32_16x16x32_bf16(     \
                CURSET[i * 2 + ks], bfr[j4], acc[i][jg * 4 + j4], 0, 0, 0);    \
      }                                                                        \
    }                                                                          \
  }

  PHASE(0, af0, af2)
  PHASE(1, af1, af0)
  PHASE(2, af2, af1)
  PHASE(3, af0, af2)
  PHASE(4, af1, af0)
  PHASE(5, af2, af0)

#undef PHASE
#undef AFLOAD
#undef STAGE

#pragma unroll
  for (int i = 0; i < 2; ++i) {
    int obase = w * 32 + i * 16 + quad * 4;
    float4 bb = *(const float4*)(bias + obase);
#pragma unroll
    for (int j = 0; j < 8; ++j) {
      int s = s0 + j * 16 + l15;
      float f0 = acc[i][j].x + bb.x;
      float f1 = acc[i][j].y + bb.y;
      float f2 = acc[i][j].z + bb.z;
      float f3 = acc[i][j].w + bb.w;
      uint2 st;
      st.x = (unsigned)f2bf(f0) | ((unsigned)f2bf(f1) << 16);
      st.y = (unsigned)f2bf(f2) | ((unsigned)f2bf(f3) << 16);
      *(uint2*)(outT + ((size_t)slice * S_SP + s) * C_CH + obase) = st;
    }
  }
}

// ---- projection conv: R2 loop + LDS-transpose epilogue -> fp32 [o][s] direct -
// Same register/pipeline structure as conv_mfma_kernel (80 VGPR + 64 AGPR).
// Epilogue: acc+bias -> LDS [16o][128s] f32 per wave (reuses Blds, 2 rounds
// over i, XOR-swizzle s^((o&7)<<2)), then coalesced float4 stores to d_out.
__global__ __launch_bounds__(256, 3) void conv_proj_kernel(
    const unsigned short* __restrict__ YT,
    const unsigned short* __restrict__ Wp,
    const float* __restrict__ biasp,
    float* __restrict__ dout)
{
  __shared__ unsigned short Blds[3][128 * 64];  // 48 KB

  int tid = threadIdx.x;
  int s0 = blockIdx.x * 128;
  int slice = blockIdx.y;
  int b = slice >> 3, l = slice & 7;
  int lh = l & 3;
  int t_lo = (lh == 0) ? 1 : 0;
  int t_hi = (lh == 3) ? 1 : 2;
  int lo = t_lo * 2, hi = t_hi * 2 + 1;

  int w = tid >> 6, lane = tid & 63;
  int quad = lane >> 4, l15 = lane & 15;
  int srow_i = lane >> 3;
  int scs = (lane & 7) ^ srow_i;

  v4f acc[2][8];
#pragma unroll
  for (int i = 0; i < 2; ++i)
#pragma unroll
    for (int j = 0; j < 8; ++j)
      acc[i][j] = (v4f){0.f, 0.f, 0.f, 0.f};

  short8 af0[4], af1[4], af2[4];

#define STAGE(ap, bsel) do {                                                   \
    int t_ = (ap) >> 1;                                                        \
    const unsigned short* gb_ =                                                \
        YT + ((size_t)(b * 8 + l - 1 + t_) * S_SP + s0) * C_CH +               \
        ((ap) & 1) * 64;                                                       \
    _Pragma("unroll")                                                          \
    for (int q_ = 0; q_ < 4; ++q_)                                             \
      gload_lds16(gb_ + (size_t)((w * 4 + q_) * 8 + srow_i) * C_CH + scs * 8,  \
                  &Blds[bsel][(w * 4 + q_) * 512]);                            \
  } while (0)

#define AFLOAD(ap, set) do {                                                   \
    _Pragma("unroll")                                                          \
    for (int i_ = 0; i_ < 2; ++i_)                                             \
      _Pragma("unroll")                                                        \
      for (int ks_ = 0; ks_ < 2; ++ks_)                                        \
        set[i_ * 2 + ks_] = *(const short8*)(                                  \
            Wp + (size_t)(w * 32 + i_ * 16 + l15) * KTOT +                     \
            (ap) * 64 + ks_ * 32 + quad * 8);                                  \
  } while (0)

  if (lo == 0) {
    STAGE(0, 0); AFLOAD(0, af0);
    __builtin_amdgcn_sched_barrier(0);
    STAGE(1, 1); AFLOAD(1, af1);
  } else {
    STAGE(2, 2); AFLOAD(2, af2);
    __builtin_amdgcn_sched_barrier(0);
    STAGE(3, 0); AFLOAD(3, af0);
  }

#define PHASE(ap, CURSET, NXTSET)                                              \
  if ((ap) >= lo && (ap) <= hi) {                                              \
    if ((ap) == hi) { asm volatile("s_waitcnt vmcnt(0)" ::: "memory"); }       \
    else            { asm volatile("s_waitcnt vmcnt(8)" ::: "memory"); }       \
    __builtin_amdgcn_s_barrier();                                              \
    if ((ap) + 2 <= hi) { STAGE((ap) + 2, ((ap) + 2) % 3);                     \
                          AFLOAD((ap) + 2, NXTSET); }                          \
    const unsigned short* Bp_ = &Blds[(ap) % 3][0];                            \
    _Pragma("unroll")                                                          \
    for (int ks = 0; ks < 2; ++ks) {                                           \
      _Pragma("unroll")                                                        \
      for (int jg = 0; jg < 2; ++jg) {                                         \
        short8 bfr[4];                                                         \
        _Pragma("unroll")                                                      \
        for (int j4 = 0; j4 < 4; ++j4)                                         \
          bfr[j4] = *(const short8*)(                                          \
              Bp_ + ((jg * 4 + j4) * 16 + l15) * 64 +                          \
              (((ks * 4 + quad) ^ (l15 & 7)) * 8));                            \
        _Pragma("unroll")                                                      \
        for (int i = 0; i < 2; ++i)                                            \
          _Pragma("unroll")                                                    \
          for (int j4 = 0; j4 < 4; ++j4)                                       \
            acc[i][jg * 4 + j4] = __builtin_amdgcn_mfma_f32_16x16x32_bf16(     \
                CURSET[i * 2 + ks], bfr[j4], acc[i][jg * 4 + j4], 0, 0, 0);    \
      }                                                                        \
    }                                                                          \
  }

  PHASE(0, af0, af2)
  PHASE(1, af1, af0)
  PHASE(2, af2, af1)
  PHASE(3, af0, af2)
  PHASE(4, af1, af0)
  PHASE(5, af2, af0)

#undef PHASE
#undef AFLOAD
#undef STAGE

  // ---- epilogue: LDS transpose -> coalesced fp32 [o][s] stores --------------
  float* fst = (float*)&Blds[0][0];   // 48 KB; 32 KB used per round
#pragma unroll
  for (int i = 0; i < 2; ++i) {
    __syncthreads();   // round 0: protect last phase ds_reads; round 1: prev reads
    {
      float4 bb = *(const float4*)(biasp + w * 32 + i * 16 + quad * 4);
      int ol0 = quad * 4;
#pragma unroll
      for (int j = 0; j < 8; ++j) {
        int s = j * 16 + l15;
        fst[w * 2048 + (ol0 + 0) * 128 + (s ^ (((ol0 + 0) & 7) << 2))] = acc[i][j].x + bb.x;
        fst[w * 2048 + (ol0 + 1) * 128 + (s ^ (((ol0 + 1) & 7) << 2))] = acc[i][j].y + bb.y;
        fst[w * 2048 + (ol0 + 2) * 128 + (s ^ (((ol0 + 2) & 7) << 2))] = acc[i][j].z + bb.z;
        fst[w * 2048 + (ol0 + 3) * 128 + (s ^ (((ol0 + 3) & 7) << 2))] = acc[i][j].w + bb.w;
      }
    }
    __syncthreads();
    {
      int o_idx = tid >> 2;                 // 0..63
      int wv = o_idx >> 4, ol = o_idx & 15;
      int o = wv * 32 + i * 16 + ol;
      int swz = (ol & 7) << 2;
      float* orow = dout + ((size_t)slice * 128 + o) * 16384 + s0;
      const float* lrow = fst + wv * 2048 + ol * 128;
#pragma unroll
      for (int u = 0; u < 8; ++u) {
        int s = (tid & 3) * 4 + u * 16;
        float4 v = *(const float4*)(lrow + (s ^ swz));
        *(float4*)(orow + s) = v;
      }
    }
  }
}

// ---- fused both-direction window attention -----------------------------------
__device__ inline void load16(const unsigned short* p, float* f) {
  uint4 a = *(const uint4*)p;
  uint4 c = *(const uint4*)(p + 8);
  unsigned v[8] = {a.x, a.y, a.z, a.w, c.x, c.y, c.z, c.w};
#pragma unroll
  for (int i = 0; i < 8; ++i) {
    f[2 * i] = bf2f((unsigned short)(v[i] & 0xffffu));
    f[2 * i + 1] = bf2f((unsigned short)(v[i] >> 16));
  }
}

__global__ __launch_bounds__(256) void attn_kernel(
    const unsigned short* __restrict__ QT,
    const unsigned short* __restrict__ KT,
    const unsigned short* __restrict__ VT,
    unsigned short* __restrict__ YT)
{
  int tid = threadIdx.x;
  int wave = tid >> 6, lane = tid & 63;
  int dir = wave & 1;
  int win = blockIdx.x * 2 + (wave >> 1);
  int by = blockIdx.y;
  int b = by >> 2, l0 = by & 3;
  int head = lane >> 3, qi = lane & 7;
  int d0 = win >> 8, h0 = (win >> 4) & 15, w0 = win & 15;
  int lq = l0 + dir * 4;
  int lk = l0 + 4 - dir * 4;
  int sE[8];
#pragma unroll
  for (int e = 0; e < 8; ++e)
    sE[e] = (2 * d0 + (e >> 2)) * 1024 + (2 * h0 + ((e >> 1) & 1)) * 32 + (2 * w0 + (e & 1));

  size_t qbase = ((size_t)(b * 8 + lq) * S_SP + sE[qi]) * C_CH + head * 16;
  size_t kslice = (size_t)(b * 8 + lk) * S_SP;
  float q[16];
  load16(QT + qbase, q);

  float lg[8];
#pragma unroll
  for (int j = 0; j < 8; ++j) {
    float kk[16];
    load16(KT + (kslice + sE[j]) * C_CH + head * 16, kk);
    float d = 0.f;
#pragma unroll
    for (int x = 0; x < 16; ++x) d += q[x] * kk[x];
    lg[j] = d * 0.25f;  // scale = (C/NH)^-0.5 = 1/4
  }
  float m = lg[0];
#pragma unroll
  for (int j = 1; j < 8; ++j) m = fmaxf(m, lg[j]);
  float p[8], sum = 0.f;
#pragma unroll
  for (int j = 0; j < 8; ++j) { p[j] = __expf(lg[j] - m); sum += p[j]; }
  float inv = 1.0f / sum;

  float y[16];
#pragma unroll
  for (int x = 0; x < 16; ++x) y[x] = 0.f;
#pragma unroll
  for (int j = 0; j < 8; ++j) {
    float vv[16];
    load16(VT + (kslice + sE[j]) * C_CH + head * 16, vv);
    float pj = p[j] * inv;
#pragma unroll
    for (int x = 0; x < 16; ++x) y[x] += pj * vv[x];
  }
  uint4 o0, o1;
  o0.x = (unsigned)f2bf(y[0]) | ((unsigned)f2bf(y[1]) << 16);
  o0.y = (unsigned)f2bf(y[2]) | ((unsigned)f2bf(y[3]) << 16);
  o0.z = (unsigned)f2bf(y[4]) | ((unsigned)f2bf(y[5]) << 16);
  o0.w = (unsigned)f2bf(y[6]) | ((unsigned)f2bf(y[7]) << 16);
  o1.x = (unsigned)f2bf(y[8]) | ((unsigned)f2bf(y[9]) << 16);
  o1.y = (unsigned)f2bf(y[10]) | ((unsigned)f2bf(y[11]) << 16);
  o1.z = (unsigned)f2bf(y[12]) | ((unsigned)f2bf(y[13]) << 16);
  o1.w = (unsigned)f2bf(y[14]) | ((unsigned)f2bf(y[15]) << 16);
  *(uint4*)(YT + qbase) = o0;
  *(uint4*)(YT + qbase + 8) = o1;
}

// -------------------------------------------------------------------------------
extern "C" void kernel_launch(void* const* d_in, const int* in_sizes, int n_in,
                              void* d_out, int out_size, void* d_ws, size_t ws_size,
                              hipStream_t stream) {
  const float* x  = (const float*)d_in[0];
  const float* wq = (const float*)d_in[1];
  const float* bq = (const float*)d_in[2];
  const float* wk = (const float*)d_in[3];
  const float* bk = (const float*)d_in[4];
  const float* wv = (const float*)d_in[5];
  const float* bv = (const float*)d_in[6];
  const float* wp = (const float*)d_in[7];
  const float* bp = (const float*)d_in[8];

  char* ws = (char*)d_ws;
  unsigned short* Wr = (unsigned short*)ws;       // 4*49152 bf16 = 393216 B
  float* biasf = (float*)(ws + 393216);           // 4*128 f32   = 2048 B
  size_t off = 395264;
  const size_t TENB = (size_t)NSLICE * S_SP * C_CH * 2;  // 67108864 B per tensor
  unsigned short* xT = (unsigned short*)(ws + off); off += TENB;
  unsigned short* QT = (unsigned short*)(ws + off); off += TENB;
  unsigned short* KT = (unsigned short*)(ws + off); off += TENB;
  unsigned short* VT = (unsigned short*)(ws + off); off += TENB;
  unsigned short* YT = xT;  // xT dead after QKV convs; reuse for attention out

  // 1) repack weights / biases (fp32 -> bf16 / fp32)
  hipLaunchKernelGGL(repack_kernel, dim3(770), dim3(256), 0, stream,
                     wq, wk, wv, wp, bq, bk, bv, bp, Wr, biasf);
  // 2) x fp32 [c][s] -> xT bf16 [s][c]
  hipLaunchKernelGGL(transpose_f2b_kernel, dim3(256, 2, 16), dim3(256), 0, stream,
                     x, xT, 128, 16384);
  // 3) Q,K,V convs (z selects weights/output; Q,K,V contiguous in ws)
  hipLaunchKernelGGL(conv_mfma_kernel, dim3(128, 16, 3), dim3(256), 0, stream,
                     xT, Wr, biasf, QT);
  // 4) fused both-direction window attention -> YT
  hipLaunchKernelGGL(attn_kernel, dim3(1024, 8), dim3(256), 0, stream,
                     QT, KT, VT, YT);
  // 5) projection conv -> direct fp32 [o][s] output (egress transpose deleted)
  hipLaunchKernelGGL(conv_proj_kernel, dim3(128, 16), dim3(256), 0, stream,
                     YT, Wr + 3 * 49152, biasf + 384, (float*)d_out);
}

// Round 5
// 446.314 us; speedup vs baseline: 1.3511x; 1.0254x over previous
//
#include <hip/hip_runtime.h>

typedef __attribute__((ext_vector_type(8))) short short8;
typedef __attribute__((ext_vector_type(4))) float v4f;

#define C_CH 128
#define S_SP 16384
#define NSLICE 16
#define KTOT 384

__device__ inline float bf2f(unsigned short u) {
  union { unsigned int i; float f; } v; v.i = ((unsigned int)u) << 16; return v.f;
}
__device__ inline unsigned short f2bf(float f) {
  union { float f; unsigned int i; } v; v.f = f;
  unsigned int u = v.i;
  return (unsigned short)((u + 0x7FFFu + ((u >> 16) & 1u)) >> 16);
}

__device__ inline void gload_lds16(const unsigned short* g, unsigned short* l) {
  __builtin_amdgcn_global_load_lds(
      (const __attribute__((address_space(1))) void*)g,
      (__attribute__((address_space(3))) void*)l, 16, 0, 0);
}

// ---- weight repack: Wr[o][t*128+c] = bf16(w[o][c][t]); bias fp32 copy --------
__global__ __launch_bounds__(256) void repack_kernel(
    const float* __restrict__ wq, const float* __restrict__ wk,
    const float* __restrict__ wv, const float* __restrict__ wp,
    const float* __restrict__ bq, const float* __restrict__ bk,
    const float* __restrict__ bv, const float* __restrict__ bp,
    unsigned short* __restrict__ Wr, float* __restrict__ biasf)
{
  int i = blockIdx.x * 256 + threadIdx.x;
  const int WN = 4 * 49152;
  if (i < WN) {
    int m = i / 49152;
    int r = i % 49152;
    int o = r / 384, k = r % 384;
    int t = k >> 7, c = k & 127;
    const float* w = (m == 0) ? wq : (m == 1) ? wk : (m == 2) ? wv : wp;
    Wr[i] = f2bf(w[o * 384 + c * 3 + t]);
  } else if (i < WN + 512) {
    int j = i - WN;
    int m = j >> 7, o = j & 127;
    const float* bb = (m == 0) ? bq : (m == 1) ? bk : (m == 2) ? bv : bp;
    biasf[j] = bb[o];
  }
}

// ---- ingress: fp32 [R][C] -> bf16 [C][R], per z-slice (R=128, C=16384) -------
__global__ __launch_bounds__(256) void transpose_f2b_kernel(
    const float* __restrict__ in, unsigned short* __restrict__ out,
    int R, int C)
{
  __shared__ unsigned short t[64][72];
  int tid = threadIdx.x;
  size_t slice = blockIdx.z;
  const float* ip = in + slice * (size_t)R * C;
  unsigned short* op = out + slice * (size_t)R * C;
  int c0 = blockIdx.x * 64, r0 = blockIdx.y * 64;
#pragma unroll
  for (int p = 0; p < 4; ++p) {
    int id = tid + p * 256;
    int row = id >> 4, col = (id & 15) * 4;
    float4 v = *(const float4*)(ip + (size_t)(r0 + row) * C + c0 + col);
    t[row][col + 0] = f2bf(v.x);
    t[row][col + 1] = f2bf(v.y);
    t[row][col + 2] = f2bf(v.z);
    t[row][col + 3] = f2bf(v.w);
  }
  __syncthreads();
#pragma unroll
  for (int p = 0; p < 2; ++p) {
    int id = tid + p * 256;
    int crow = id >> 3, rcol = (id & 7) * 8;
    uint4 v;
    v.x = (unsigned)t[rcol + 0][crow] | ((unsigned)t[rcol + 1][crow] << 16);
    v.y = (unsigned)t[rcol + 2][crow] | ((unsigned)t[rcol + 3][crow] << 16);
    v.z = (unsigned)t[rcol + 4][crow] | ((unsigned)t[rcol + 5][crow] << 16);
    v.w = (unsigned)t[rcol + 6][crow] | ((unsigned)t[rcol + 7][crow] << 16);
    *(uint4*)(op + (size_t)(c0 + crow) * R + r0 + rcol) = v;
  }
}

// ---- MFMA conv (R2-proven): per-phase A regs (3 rotating sets), tri-buffer B,
// depth-2 counted-vmcnt pipeline. out[slice][s][o] bf16.
__global__ __launch_bounds__(256, 3) void conv_mfma_kernel(
    const unsigned short* __restrict__ inT,
    const unsigned short* __restrict__ Wr_all,
    const float* __restrict__ bias_all,
    unsigned short* __restrict__ outT_all)
{
  __shared__ unsigned short Blds[3][128 * 64];  // 3 x 16 KB, linear (swizzled)

  int z = blockIdx.z;
  const unsigned short* Wr = Wr_all + (size_t)z * 49152;
  const float* bias = bias_all + z * 128;
  unsigned short* outT = outT_all + (size_t)z * NSLICE * S_SP * C_CH;

  int tid = threadIdx.x;
  int s0 = blockIdx.x * 128;
  int slice = blockIdx.y;
  int b = slice >> 3, l = slice & 7;
  int lh = l & 3;
  int t_lo = (lh == 0) ? 1 : 0;
  int t_hi = (lh == 3) ? 1 : 2;
  int lo = t_lo * 2, hi = t_hi * 2 + 1;

  int w = tid >> 6, lane = tid & 63;
  int quad = lane >> 4, l15 = lane & 15;
  int srow_i = lane >> 3;
  int scs = (lane & 7) ^ srow_i;

  v4f acc[2][8];
#pragma unroll
  for (int i = 0; i < 2; ++i)
#pragma unroll
    for (int j = 0; j < 8; ++j)
      acc[i][j] = (v4f){0.f, 0.f, 0.f, 0.f};

  short8 af0[4], af1[4], af2[4];

#define STAGE(ap, bsel) do {                                                   \
    int t_ = (ap) >> 1;                                                        \
    const unsigned short* gb_ =                                                \
        inT + ((size_t)(b * 8 + l - 1 + t_) * S_SP + s0) * C_CH +              \
        ((ap) & 1) * 64;                                                       \
    _Pragma("unroll")                                                          \
    for (int q_ = 0; q_ < 4; ++q_)                                             \
      gload_lds16(gb_ + (size_t)((w * 4 + q_) * 8 + srow_i) * C_CH + scs * 8,  \
                  &Blds[bsel][(w * 4 + q_) * 512]);                            \
  } while (0)

#define AFLOAD(ap, set) do {                                                   \
    _Pragma("unroll")                                                          \
    for (int i_ = 0; i_ < 2; ++i_)                                             \
      _Pragma("unroll")                                                        \
      for (int ks_ = 0; ks_ < 2; ++ks_)                                        \
        set[i_ * 2 + ks_] = *(const short8*)(                                  \
            Wr + (size_t)(w * 32 + i_ * 16 + l15) * KTOT +                     \
            (ap) * 64 + ks_ * 32 + quad * 8);                                  \
  } while (0)

  if (lo == 0) {
    STAGE(0, 0); AFLOAD(0, af0);
    __builtin_amdgcn_sched_barrier(0);
    STAGE(1, 1); AFLOAD(1, af1);
  } else {
    STAGE(2, 2); AFLOAD(2, af2);
    __builtin_amdgcn_sched_barrier(0);
    STAGE(3, 0); AFLOAD(3, af0);
  }

#define PHASE(ap, CURSET, NXTSET)                                              \
  if ((ap) >= lo && (ap) <= hi) {                                              \
    if ((ap) == hi) { asm volatile("s_waitcnt vmcnt(0)" ::: "memory"); }       \
    else            { asm volatile("s_waitcnt vmcnt(8)" ::: "memory"); }       \
    __builtin_amdgcn_s_barrier();                                              \
    if ((ap) + 2 <= hi) { STAGE((ap) + 2, ((ap) + 2) % 3);                     \
                          AFLOAD((ap) + 2, NXTSET); }                          \
    const unsigned short* Bp_ = &Blds[(ap) % 3][0];                            \
    _Pragma("unroll")                                                          \
    for (int ks = 0; ks < 2; ++ks) {                                           \
      _Pragma("unroll")                                                        \
      for (int jg = 0; jg < 2; ++jg) {                                         \
        short8 bfr[4];                                                         \
        _Pragma("unroll")                                                      \
        for (int j4 = 0; j4 < 4; ++j4)                                         \
          bfr[j4] = *(const short8*)(                                          \
              Bp_ + ((jg * 4 + j4) * 16 + l15) * 64 +                          \
              (((ks * 4 + quad) ^ (l15 & 7)) * 8));                            \
        _Pragma("unroll")                                                      \
        for (int i = 0; i < 2; ++i)                                            \
          _Pragma("unroll")                                                    \
          for (int j4 = 0; j4 < 4; ++j4)                                       \
            acc[i][jg * 4 + j4] = __builtin_amdgcn_mfma_f32_16x16x32_bf16(     \
                CURSET[i * 2 + ks], bfr[j4], acc[i][jg * 4 + j4], 0, 0, 0);    \
      }                                                                        \
    }                                                                          \
  }

  PHASE(0, af0, af2)
  PHASE(1, af1, af0)
  PHASE(2, af2, af1)
  PHASE(3, af0, af2)
  PHASE(4, af1, af0)
  PHASE(5, af2, af0)

#undef PHASE
#undef AFLOAD
#undef STAGE

#pragma unroll
  for (int i = 0; i < 2; ++i) {
    int obase = w * 32 + i * 16 + quad * 4;
    float4 bb = *(const float4*)(bias + obase);
#pragma unroll
    for (int j = 0; j < 8; ++j) {
      int s = s0 + j * 16 + l15;
      float f0 = acc[i][j].x + bb.x;
      float f1 = acc[i][j].y + bb.y;
      float f2 = acc[i][j].z + bb.z;
      float f3 = acc[i][j].w + bb.w;
      uint2 st;
      st.x = (unsigned)f2bf(f0) | ((unsigned)f2bf(f1) << 16);
      st.y = (unsigned)f2bf(f2) | ((unsigned)f2bf(f3) << 16);
      *(uint2*)(outT + ((size_t)slice * S_SP + s) * C_CH + obase) = st;
    }
  }
}

// ---- projection conv: R2 loop + LDS-transpose epilogue -> fp32 [o][s] direct -
__global__ __launch_bounds__(256, 3) void conv_proj_kernel(
    const unsigned short* __restrict__ YT,
    const unsigned short* __restrict__ Wp,
    const float* __restrict__ biasp,
    float* __restrict__ dout)
{
  __shared__ unsigned short Blds[3][128 * 64];  // 48 KB

  int tid = threadIdx.x;
  int s0 = blockIdx.x * 128;
  int slice = blockIdx.y;
  int b = slice >> 3, l = slice & 7;
  int lh = l & 3;
  int t_lo = (lh == 0) ? 1 : 0;
  int t_hi = (lh == 3) ? 1 : 2;
  int lo = t_lo * 2, hi = t_hi * 2 + 1;

  int w = tid >> 6, lane = tid & 63;
  int quad = lane >> 4, l15 = lane & 15;
  int srow_i = lane >> 3;
  int scs = (lane & 7) ^ srow_i;

  v4f acc[2][8];
#pragma unroll
  for (int i = 0; i < 2; ++i)
#pragma unroll
    for (int j = 0; j < 8; ++j)
      acc[i][j] = (v4f){0.f, 0.f, 0.f, 0.f};

  short8 af0[4], af1[4], af2[4];

#define STAGE(ap, bsel) do {                                                   \
    int t_ = (ap) >> 1;                                                        \
    const unsigned short* gb_ =                                                \
        YT + ((size_t)(b * 8 + l - 1 + t_) * S_SP + s0) * C_CH +               \
        ((ap) & 1) * 64;                                                       \
    _Pragma("unroll")                                                          \
    for (int q_ = 0; q_ < 4; ++q_)                                             \
      gload_lds16(gb_ + (size_t)((w * 4 + q_) * 8 + srow_i) * C_CH + scs * 8,  \
                  &Blds[bsel][(w * 4 + q_) * 512]);                            \
  } while (0)

#define AFLOAD(ap, set) do {                                                   \
    _Pragma("unroll")                                                          \
    for (int i_ = 0; i_ < 2; ++i_)                                             \
      _Pragma("unroll")                                                        \
      for (int ks_ = 0; ks_ < 2; ++ks_)                                        \
        set[i_ * 2 + ks_] = *(const short8*)(                                  \
            Wp + (size_t)(w * 32 + i_ * 16 + l15) * KTOT +                     \
            (ap) * 64 + ks_ * 32 + quad * 8);                                  \
  } while (0)

  if (lo == 0) {
    STAGE(0, 0); AFLOAD(0, af0);
    __builtin_amdgcn_sched_barrier(0);
    STAGE(1, 1); AFLOAD(1, af1);
  } else {
    STAGE(2, 2); AFLOAD(2, af2);
    __builtin_amdgcn_sched_barrier(0);
    STAGE(3, 0); AFLOAD(3, af0);
  }

#define PHASE(ap, CURSET, NXTSET)                                              \
  if ((ap) >= lo && (ap) <= hi) {                                              \
    if ((ap) == hi) { asm volatile("s_waitcnt vmcnt(0)" ::: "memory"); }       \
    else            { asm volatile("s_waitcnt vmcnt(8)" ::: "memory"); }       \
    __builtin_amdgcn_s_barrier();                                              \
    if ((ap) + 2 <= hi) { STAGE((ap) + 2, ((ap) + 2) % 3);                     \
                          AFLOAD((ap) + 2, NXTSET); }                          \
    const unsigned short* Bp_ = &Blds[(ap) % 3][0];                            \
    _Pragma("unroll")                                                          \
    for (int ks = 0; ks < 2; ++ks) {                                           \
      _Pragma("unroll")                                                        \
      for (int jg = 0; jg < 2; ++jg) {                                         \
        short8 bfr[4];                                                         \
        _Pragma("unroll")                                                      \
        for (int j4 = 0; j4 < 4; ++j4)                                         \
          bfr[j4] = *(const short8*)(                                          \
              Bp_ + ((jg * 4 + j4) * 16 + l15) * 64 +                          \
              (((ks * 4 + quad) ^ (l15 & 7)) * 8));                            \
        _Pragma("unroll")                                                      \
        for (int i = 0; i < 2; ++i)                                            \
          _Pragma("unroll")                                                    \
          for (int j4 = 0; j4 < 4; ++j4)                                       \
            acc[i][jg * 4 + j4] = __builtin_amdgcn_mfma_f32_16x16x32_bf16(     \
                CURSET[i * 2 + ks], bfr[j4], acc[i][jg * 4 + j4], 0, 0, 0);    \
      }                                                                        \
    }                                                                          \
  }

  PHASE(0, af0, af2)
  PHASE(1, af1, af0)
  PHASE(2, af2, af1)
  PHASE(3, af0, af2)
  PHASE(4, af1, af0)
  PHASE(5, af2, af0)

#undef PHASE
#undef AFLOAD
#undef STAGE

  // ---- epilogue: LDS transpose -> coalesced fp32 [o][s] stores --------------
  float* fst = (float*)&Blds[0][0];
#pragma unroll
  for (int i = 0; i < 2; ++i) {
    __syncthreads();
    {
      float4 bb = *(const float4*)(biasp + w * 32 + i * 16 + quad * 4);
      int ol0 = quad * 4;
#pragma unroll
      for (int j = 0; j < 8; ++j) {
        int s = j * 16 + l15;
        fst[w * 2048 + (ol0 + 0) * 128 + (s ^ (((ol0 + 0) & 7) << 2))] = acc[i][j].x + bb.x;
        fst[w * 2048 + (ol0 + 1) * 128 + (s ^ (((ol0 + 1) & 7) << 2))] = acc[i][j].y + bb.y;
        fst[w * 2048 + (ol0 + 2) * 128 + (s ^ (((ol0 + 2) & 7) << 2))] = acc[i][j].z + bb.z;
        fst[w * 2048 + (ol0 + 3) * 128 + (s ^ (((ol0 + 3) & 7) << 2))] = acc[i][j].w + bb.w;
      }
    }
    __syncthreads();
    {
      int o_idx = tid >> 2;
      int wv = o_idx >> 4, ol = o_idx & 15;
      int o = wv * 32 + i * 16 + ol;
      int swz = (ol & 7) << 2;
      float* orow = dout + ((size_t)slice * 128 + o) * 16384 + s0;
      const float* lrow = fst + wv * 2048 + ol * 128;
#pragma unroll
      for (int u = 0; u < 8; ++u) {
        int s = (tid & 3) * 4 + u * 16;
        float4 v = *(const float4*)(lrow + (s ^ swz));
        *(float4*)(orow + s) = v;
      }
    }
  }
}

// ---- fused both-direction window attention (K/V LDS-dedup) -------------------
__device__ inline void load16(const unsigned short* p, float* f) {
  uint4 a = *(const uint4*)p;
  uint4 c = *(const uint4*)(p + 8);
  unsigned v[8] = {a.x, a.y, a.z, a.w, c.x, c.y, c.z, c.w};
#pragma unroll
  for (int i = 0; i < 8; ++i) {
    f[2 * i] = bf2f((unsigned short)(v[i] & 0xffffu));
    f[2 * i + 1] = bf2f((unsigned short)(v[i] >> 16));
  }
}

__global__ __launch_bounds__(256) void attn_kernel(
    const unsigned short* __restrict__ QT,
    const unsigned short* __restrict__ KT,
    const unsigned short* __restrict__ VT,
    unsigned short* __restrict__ YT)
{
  // per-wave K/V tiles: 8 pos x 128 ch bf16 each (2 KB + 2 KB)
  __shared__ unsigned short kv[4][2048];
  int tid = threadIdx.x;
  int wave = tid >> 6, lane = tid & 63;
  int dir = wave & 1;
  int win = blockIdx.x * 2 + (wave >> 1);
  int by = blockIdx.y;
  int b = by >> 2, l0 = by & 3;
  int head = lane >> 3, qi = lane & 7;
  int d0 = win >> 8, h0 = (win >> 4) & 15, w0 = win & 15;
  int lq = l0 + dir * 4;
  int lk = l0 + 4 - dir * 4;
  size_t kslice = (size_t)(b * 8 + lk) * S_SP;

  unsigned short* kw = &kv[wave][0];
  // stage K,V: linear tile byte i*1024 + lane*16 <- pos e, chunk (lane&15)*16B
  {
    int off = (lane & 15) * 8;  // shorts
#pragma unroll
    for (int i = 0; i < 2; ++i) {
      int e = i * 4 + (lane >> 4);
      int se = (2 * d0 + (e >> 2)) * 1024 + (2 * h0 + ((e >> 1) & 1)) * 32 + (2 * w0 + (e & 1));
      gload_lds16(KT + (kslice + se) * C_CH + off, kw + i * 512);
      gload_lds16(VT + (kslice + se) * C_CH + off, kw + 1024 + i * 512);
    }
  }

  int sq = (2 * d0 + (qi >> 2)) * 1024 + (2 * h0 + ((qi >> 1) & 1)) * 32 + (2 * w0 + (qi & 1));
  size_t qbase = ((size_t)(b * 8 + lq) * S_SP + sq) * C_CH + head * 16;
  float q[16];
  load16(QT + qbase, q);

  asm volatile("s_waitcnt vmcnt(0)" ::: "memory");

  float lg[8];
#pragma unroll
  for (int j = 0; j < 8; ++j) {
    float kk[16];
    load16(kw + j * 128 + head * 16, kk);
    float d = 0.f;
#pragma unroll
    for (int x = 0; x < 16; ++x) d += q[x] * kk[x];
    lg[j] = d * 0.25f;  // scale = (C/NH)^-0.5 = 1/4
  }
  float m = lg[0];
#pragma unroll
  for (int j = 1; j < 8; ++j) m = fmaxf(m, lg[j]);
  float p[8], sum = 0.f;
#pragma unroll
  for (int j = 0; j < 8; ++j) { p[j] = __expf(lg[j] - m); sum += p[j]; }
  float inv = 1.0f / sum;

  float y[16];
#pragma unroll
  for (int x = 0; x < 16; ++x) y[x] = 0.f;
#pragma unroll
  for (int j = 0; j < 8; ++j) {
    float vv[16];
    load16(kw + 1024 + j * 128 + head * 16, vv);
    float pj = p[j] * inv;
#pragma unroll
    for (int x = 0; x < 16; ++x) y[x] += pj * vv[x];
  }
  uint4 o0, o1;
  o0.x = (unsigned)f2bf(y[0]) | ((unsigned)f2bf(y[1]) << 16);
  o0.y = (unsigned)f2bf(y[2]) | ((unsigned)f2bf(y[3]) << 16);
  o0.z = (unsigned)f2bf(y[4]) | ((unsigned)f2bf(y[5]) << 16);
  o0.w = (unsigned)f2bf(y[6]) | ((unsigned)f2bf(y[7]) << 16);
  o1.x = (unsigned)f2bf(y[8]) | ((unsigned)f2bf(y[9]) << 16);
  o1.y = (unsigned)f2bf(y[10]) | ((unsigned)f2bf(y[11]) << 16);
  o1.z = (unsigned)f2bf(y[12]) | ((unsigned)f2bf(y[13]) << 16);
  o1.w = (unsigned)f2bf(y[14]) | ((unsigned)f2bf(y[15]) << 16);
  *(uint4*)(YT + qbase) = o0;
  *(uint4*)(YT + qbase + 8) = o1;
}

// -------------------------------------------------------------------------------
extern "C" void kernel_launch(void* const* d_in, const int* in_sizes, int n_in,
                              void* d_out, int out_size, void* d_ws, size_t ws_size,
                              hipStream_t stream) {
  const float* x  = (const float*)d_in[0];
  const float* wq = (const float*)d_in[1];
  const float* bq = (const float*)d_in[2];
  const float* wk = (const float*)d_in[3];
  const float* bk = (const float*)d_in[4];
  const float* wv = (const float*)d_in[5];
  const float* bv = (const float*)d_in[6];
  const float* wp = (const float*)d_in[7];
  const float* bp = (const float*)d_in[8];

  char* ws = (char*)d_ws;
  unsigned short* Wr = (unsigned short*)ws;       // 4*49152 bf16 = 393216 B
  float* biasf = (float*)(ws + 393216);           // 4*128 f32   = 2048 B
  size_t off = 395264;
  const size_t TENB = (size_t)NSLICE * S_SP * C_CH * 2;  // 67108864 B per tensor
  const size_t TENE = (size_t)NSLICE * S_SP * C_CH;      // elements per tensor
  unsigned short* xT = (unsigned short*)(ws + off); off += TENB;
  unsigned short* QT = (unsigned short*)(ws + off); off += TENB;
  unsigned short* KT = (unsigned short*)(ws + off); off += TENB;
  unsigned short* VT = (unsigned short*)(ws + off); off += TENB;
  unsigned short* YT = xT;  // xT dead after QKV convs; reuse for attention out

  // 1) repack weights / biases (fp32 -> bf16 / fp32)
  hipLaunchKernelGGL(repack_kernel, dim3(770), dim3(256), 0, stream,
                     wq, wk, wv, wp, bq, bk, bv, bp, Wr, biasf);
  // 2) x fp32 [c][s] -> xT bf16 [s][c]
  hipLaunchKernelGGL(transpose_f2b_kernel, dim3(256, 2, 16), dim3(256), 0, stream,
                     x, xT, 128, 16384);
  // 3) Q,K,V convs — split into 3 dispatches (visibility: lowers top-5 cutoff)
  for (int z = 0; z < 3; ++z)
    hipLaunchKernelGGL(conv_mfma_kernel, dim3(128, 16, 1), dim3(256), 0, stream,
                       xT, Wr + (size_t)z * 49152, biasf + z * 128,
                       QT + (size_t)z * TENE);
  // 4) fused both-direction window attention -> YT
  hipLaunchKernelGGL(attn_kernel, dim3(1024, 8), dim3(256), 0, stream,
                     QT, KT, VT, YT);
  // 5) projection conv -> direct fp32 [o][s] output
  hipLaunchKernelGGL(conv_proj_kernel, dim3(128, 16), dim3(256), 0, stream,
                     YT, Wr + 3 * 49152, biasf + 384, (float*)d_out);
}